// Round 1
// baseline (630.500 us; speedup 1.0000x reference)
//
#include <hip/hip_runtime.h>

// Problem: out = tanh(sign(X) @ sign(W) + bias)
//   X: [8192, 4096] fp32, W: [4096, 4096] fp32, bias: [4096] fp32, out fp32.
// Strategy: binarize to bf16 +-1 (exact), bf16 MFMA GEMM (m97 128x128 structure),
// fused bias+tanh epilogue.

#define B_DIM 8192
#define K_DIM 4096
#define N_DIM 4096

typedef float f32x4 __attribute__((ext_vector_type(4)));
typedef short bf16x8 __attribute__((ext_vector_type(8)));

#define BF16_POS ((short)0x3F80)   // +1.0 bf16
#define BF16_NEG ((short)0xBF80)   // -1.0 bf16

__device__ __forceinline__ short binq(float v) {
    // matches jnp.where(x < 0, -1.0, 1.0): x==0 (and -0.0) -> +1
    return (v < 0.0f) ? BF16_NEG : BF16_POS;
}

// ---- Prepass 1: binarize inputs X -> bf16 [B_DIM][K_DIM] (same layout) ----
__global__ __launch_bounds__(256) void binarize_a_kernel(
    const float* __restrict__ in, unsigned short* __restrict__ out, long n8) {
    long i = (long)blockIdx.x * blockDim.x + threadIdx.x;
    const long stride = (long)gridDim.x * blockDim.x;
    for (; i < n8; i += stride) {
        const float4* p = (const float4*)in + 2 * i;
        float4 v0 = p[0];
        float4 v1 = p[1];
        bf16x8 o;
        o[0] = binq(v0.x); o[1] = binq(v0.y); o[2] = binq(v0.z); o[3] = binq(v0.w);
        o[4] = binq(v1.x); o[5] = binq(v1.y); o[6] = binq(v1.z); o[7] = binq(v1.w);
        *(bf16x8*)(out + i * 8) = o;
    }
}

// ---- Prepass 2: binarize + transpose W [K][N] -> Bt bf16 [N][K] ----
__global__ __launch_bounds__(256) void bintrans_kernel(
    const float* __restrict__ W, unsigned short* __restrict__ Bt) {
    __shared__ unsigned short tile[32][33];   // +1 pad breaks bank conflicts
    const int n0 = blockIdx.x * 32;
    const int k0 = blockIdx.y * 32;
    const int tx = threadIdx.x;   // 0..31
    const int ty = threadIdx.y;   // 0..7
#pragma unroll
    for (int i = 0; i < 4; ++i) {
        int k = k0 + ty + i * 8;
        float v = W[(size_t)k * N_DIM + n0 + tx];
        tile[ty + i * 8][tx] = (unsigned short)binq(v);
    }
    __syncthreads();
#pragma unroll
    for (int i = 0; i < 4; ++i) {
        int n = n0 + ty + i * 8;
        Bt[(size_t)n * K_DIM + k0 + tx] = tile[tx][ty + i * 8];
    }
}

// ---- Main GEMM: C = tanh(A_bin @ Bt_bin^T + bias) ----
// A: [B_DIM][K_DIM] bf16, Bt: [N_DIM][K_DIM] bf16 (i.e. classic B^T GEMM).
// 128x128 tile, BK=32, 4 waves in 2x2, each wave 4x4 frags of 16x16x32 MFMA.
__global__ __launch_bounds__(256) void bgemm_kernel(
    const unsigned short* __restrict__ A,
    const unsigned short* __restrict__ Bt,
    const float* __restrict__ bias,
    float* __restrict__ C) {
    __shared__ unsigned short As[128 * 32];   // 8 KB, linear (global_load_lds dest)
    __shared__ unsigned short Bs[128 * 32];   // 8 KB

    const int tid  = threadIdx.x;
    const int lane = tid & 63;
    const int wid  = tid >> 6;    // 0..3
    const int wr   = wid >> 1;    // wave row (0..1)
    const int wc   = wid & 1;     // wave col (0..1)

    // XCD-aware block swizzle (nwg = 2048, divisible by 8)
    const int nwg = gridDim.x;
    const int wg  = blockIdx.x;
    int swz = wg;
    if ((nwg & 7) == 0) {
        const int per = nwg >> 3;
        swz = (wg & 7) * per + (wg >> 3);
    }
    const int NBN = N_DIM / 128;  // 32
    const int bm = swz / NBN;
    const int bn = swz % NBN;

    const unsigned short* Ag = A  + (size_t)bm * 128 * K_DIM;
    const unsigned short* Bg = Bt + (size_t)bn * 128 * K_DIM;

    // staging geometry: chunk = 1KB = 16 rows of 64B; lane covers 16B
    const int srow = lane >> 2;          // row within 16-row chunk
    const int scol = (lane & 3) * 8;     // bf16 element offset in row

    const f32x4 zero = {0.f, 0.f, 0.f, 0.f};
    f32x4 acc[4][4];
#pragma unroll
    for (int m = 0; m < 4; ++m)
#pragma unroll
        for (int n = 0; n < 4; ++n) acc[m][n] = zero;

    for (int k0 = 0; k0 < K_DIM; k0 += 32) {
        __syncthreads();   // previous iter's ds_reads done before overwrite
#pragma unroll
        for (int i = 0; i < 2; ++i) {
            const int c   = wid * 2 + i;          // chunk 0..7
            const int row = c * 16 + srow;        // tile row 0..127
            __builtin_amdgcn_global_load_lds(
                (const __attribute__((address_space(1))) void*)(Ag + (size_t)row * K_DIM + k0 + scol),
                (__attribute__((address_space(3))) void*)(As + c * 512),
                16, 0, 0);
            __builtin_amdgcn_global_load_lds(
                (const __attribute__((address_space(1))) void*)(Bg + (size_t)row * K_DIM + k0 + scol),
                (__attribute__((address_space(3))) void*)(Bs + c * 512),
                16, 0, 0);
        }
        __syncthreads();   // compiler drains vmcnt(0) before s_barrier

        bf16x8 a[4], b[4];
#pragma unroll
        for (int m = 0; m < 4; ++m)
            a[m] = *(const bf16x8*)(As + (wr * 64 + m * 16 + (lane & 15)) * 32 + (lane >> 4) * 8);
#pragma unroll
        for (int n = 0; n < 4; ++n)
            b[n] = *(const bf16x8*)(Bs + (wc * 64 + n * 16 + (lane & 15)) * 32 + (lane >> 4) * 8);
#pragma unroll
        for (int m = 0; m < 4; ++m)
#pragma unroll
            for (int n = 0; n < 4; ++n)
                acc[m][n] = __builtin_amdgcn_mfma_f32_16x16x32_bf16(a[m], b[n], acc[m][n], 0, 0, 0);
    }

    // Epilogue: C/D layout col = lane&15, row = (lane>>4)*4 + reg
    const int cn = lane & 15;
    const int cr = (lane >> 4) * 4;
    float bv[4];
#pragma unroll
    for (int n = 0; n < 4; ++n)
        bv[n] = bias[bn * 128 + wc * 64 + n * 16 + cn];

#pragma unroll
    for (int m = 0; m < 4; ++m) {
        const int row0 = bm * 128 + wr * 64 + m * 16 + cr;
#pragma unroll
        for (int n = 0; n < 4; ++n) {
            const int col = bn * 128 + wc * 64 + n * 16 + cn;
#pragma unroll
            for (int r = 0; r < 4; ++r) {
                C[(size_t)(row0 + r) * N_DIM + col] = tanhf(acc[m][n][r] + bv[n]);
            }
        }
    }
}

extern "C" void kernel_launch(void* const* d_in, const int* in_sizes, int n_in,
                              void* d_out, int out_size, void* d_ws, size_t ws_size,
                              hipStream_t stream) {
    const float* inputs = (const float*)d_in[0];   // [8192, 4096]
    const float* weight = (const float*)d_in[1];   // [4096, 4096]
    const float* bias   = (const float*)d_in[2];   // [4096]
    float* out = (float*)d_out;

    const size_t a_bytes = (size_t)B_DIM * K_DIM * sizeof(unsigned short); // 67 MB
    const size_t b_bytes = (size_t)K_DIM * N_DIM * sizeof(unsigned short); // 33.5 MB
    if (ws_size < a_bytes + b_bytes) return;  // insufficient scratch: bail (safe no-op)

    unsigned short* Abin = (unsigned short*)d_ws;
    unsigned short* Btb  = (unsigned short*)((char*)d_ws + a_bytes);

    binarize_a_kernel<<<2048, 256, 0, stream>>>(inputs, Abin, (long)B_DIM * K_DIM / 8);

    dim3 tgrid(N_DIM / 32, K_DIM / 32);
    bintrans_kernel<<<tgrid, dim3(32, 8), 0, stream>>>(weight, Btb);

    bgemm_kernel<<<(B_DIM / 128) * (N_DIM / 128), 256, 0, stream>>>(Abin, Btb, bias, out);
}

// Round 2
// 488.737 us; speedup vs baseline: 1.2901x; 1.2901x over previous
//
#include <hip/hip_runtime.h>

// out = tanh(sign(X) @ sign(W) + bias)
//   X: [8192,4096] fp32, W: [4096,4096] fp32, bias: [4096] fp32, out fp32.
// Binarize to bf16 +-1 (exact), then 256x256-tile bf16 MFMA GEMM with the
// 8-phase counted-vmcnt pipeline (4-buffer LDS ring, BK=32), XOR-swizzled LDS.

#define B_DIM 8192
#define K_DIM 4096
#define N_DIM 4096
#define BK 32
#define NT (K_DIM / BK)   // 128 K-tiles

typedef float f32x4 __attribute__((ext_vector_type(4)));
typedef short bf16x8 __attribute__((ext_vector_type(8)));
typedef unsigned short u16;

#define BF16_POS ((short)0x3F80)
#define BF16_NEG ((short)0xBF80)

__device__ __forceinline__ short binq(float v) {
    return (v < 0.0f) ? BF16_NEG : BF16_POS;   // x==0 -> +1 (matches jnp.where)
}

__device__ __forceinline__ float fast_tanh(float x) {
    float ax = __builtin_fabsf(x);
    float t  = __expf(-2.0f * ax);                       // exact 0 for large ax
    float r  = (1.0f - t) * __builtin_amdgcn_rcpf(1.0f + t);
    return __builtin_copysignf(r, x);
}

// ---- Prepass 1: binarize X -> bf16 [B_DIM][K_DIM] ----
__global__ __launch_bounds__(256) void binarize_a_kernel(
    const float* __restrict__ in, u16* __restrict__ out, long n8) {
    long i = (long)blockIdx.x * blockDim.x + threadIdx.x;
    const long stride = (long)gridDim.x * blockDim.x;
    for (; i < n8; i += stride) {
        const float4* p = (const float4*)in + 2 * i;
        float4 v0 = p[0];
        float4 v1 = p[1];
        bf16x8 o;
        o[0] = binq(v0.x); o[1] = binq(v0.y); o[2] = binq(v0.z); o[3] = binq(v0.w);
        o[4] = binq(v1.x); o[5] = binq(v1.y); o[6] = binq(v1.z); o[7] = binq(v1.w);
        *(bf16x8*)(out + i * 8) = o;
    }
}

// ---- Prepass 2: binarize + transpose W [K][N] -> Bt bf16 [N][K] ----
__global__ __launch_bounds__(256) void bintrans_kernel(
    const float* __restrict__ W, u16* __restrict__ Bt) {
    __shared__ u16 tile[32][33];
    const int n0 = blockIdx.x * 32;
    const int k0 = blockIdx.y * 32;
    const int tx = threadIdx.x;
    const int ty = threadIdx.y;
#pragma unroll
    for (int i = 0; i < 4; ++i) {
        int k = k0 + ty + i * 8;
        float v = W[(size_t)k * N_DIM + n0 + tx];
        tile[ty + i * 8][tx] = (u16)binq(v);
    }
    __syncthreads();
#pragma unroll
    for (int i = 0; i < 4; ++i) {
        int n = n0 + ty + i * 8;
        Bt[(size_t)n * K_DIM + k0 + tx] = tile[tx][ty + i * 8];
    }
}

// ---- Main GEMM: 256x256 tile, BK=32, 8 waves (2Mx4N), wave tile 128x64 ----
// LDS: 4-buffer ring, each buffer = A[256][32] + B[256][32] bf16 = 32 KB -> 128 KB.
// XOR swizzle: row r's 16B slot s holds logical slot s ^ ((r>>1)&3); applied on
// staging SOURCE address and ds_read address (involution, rule #21).
// Pipeline: prefetch distance 3 tiles; vmcnt(8) once per tile (2 tiles in flight).
__global__ __launch_bounds__(512, 2) void bgemm_kernel(
    const u16* __restrict__ A,
    const u16* __restrict__ Bt,
    const float* __restrict__ bias,
    float* __restrict__ C) {

    __shared__ __align__(1024) char lds[131072];

    const int tid = threadIdx.x;
    const int l   = tid & 63;
    const int w   = tid >> 6;     // 0..7
    const int wr  = w >> 2;       // 0..1
    const int wc  = w & 3;        // 0..3

    // XCD-aware bijective swizzle (grid = 512, divisible by 8)
    const int wg  = blockIdx.x;
    const int per = gridDim.x >> 3;
    const int swz = (wg & 7) * per + (wg >> 3);
    const int NBN = N_DIM / 256;          // 16
    const int bm  = swz / NBN;
    const int bn  = swz % NBN;

    // ---- staging addressing (per-lane) ----
    // global_load_lds i covers LDS bytes i*8192 + tid*16 -> row = i*128 + (tid>>2),
    // slot = tid&3.  Source logical slot = (tid&3) ^ sigma(row), sigma(row)=(row>>1)&3
    // = (tid>>3)&3 (row bit1..2 come from tid>>3 since i*128 contributes 0 mod 4).
    const int sslot = (tid & 3) ^ ((tid >> 3) & 3);
    const u16* A0 = A  + (size_t)(bm * 256 + (tid >> 2)) * K_DIM + sslot * 8;
    const u16* B0 = Bt + (size_t)(bn * 256 + (tid >> 2)) * K_DIM + sslot * 8;
    const int ldsA_st = w * 1024;            // + i*8192 + bufbase
    const int ldsB_st = 16384 + w * 1024;    // B region at +16 KB

    // ---- fragment read addressing (per-lane) ----
    // logical: row = fragbase + (l&15), slot g = l>>4 (8 bf16 = 16B each).
    // swizzled slot = g ^ ((row>>1)&3); (row>>1)&3 == ((l&15)>>1)&3 == (l>>1)&3
    // since fragbase is a multiple of 16.
    const int colb = ((l >> 4) ^ ((l >> 1) & 3)) << 4;
    const int aoff = (wr * 128 + (l & 15)) * 64 + colb;            // A region
    const int boff = 16384 + (wc * 64 + (l & 15)) * 64 + colb;     // B region

#define GLL(srcp, ldsoff)                                                        \
    __builtin_amdgcn_global_load_lds(                                            \
        (const __attribute__((address_space(1))) void*)(srcp),                   \
        (__attribute__((address_space(3))) void*)(lds + (ldsoff)), 16, 0, 0)

    f32x4 acc[8][4];
#pragma unroll
    for (int mf = 0; mf < 8; ++mf)
#pragma unroll
        for (int nf = 0; nf < 4; ++nf) acc[mf][nf] = (f32x4){0.f, 0.f, 0.f, 0.f};

    // ---- prologue: stage S(0), S(1), S(2) -> buffers 0,1,2 (12 loads) ----
#pragma unroll
    for (int tp = 0; tp < 3; ++tp) {
        const int db = tp << 15;
        const int kk = tp * BK;
        GLL(A0 + kk,                          db + ldsA_st);
        GLL(A0 + (size_t)128 * K_DIM + kk,    db + ldsA_st + 8192);
        GLL(B0 + kk,                          db + ldsB_st);
        GLL(B0 + (size_t)128 * K_DIM + kk,    db + ldsB_st + 8192);
    }
    asm volatile("s_waitcnt vmcnt(8)" ::: "memory");   // S(0) landed
    __builtin_amdgcn_s_barrier();

    for (int t = 0; t < NT; ++t) {
        const int cur = (t & 3) << 15;
        const int db  = ((t + 3) & 3) << 15;
        const int tp  = (t + 3 < NT) ? (t + 3) : 0;    // dummy re-stage at tail
        const int kk  = tp * BK;

        bf16x8 a[4], b[4];

        // ================= phase A: stage A-tile of S(t+3); MFMA mf 0..3 =====
        GLL(A0 + kk,                       db + ldsA_st);
        GLL(A0 + (size_t)128 * K_DIM + kk, db + ldsA_st + 8192);
#pragma unroll
        for (int nf = 0; nf < 4; ++nf)
            b[nf] = *(const bf16x8*)(lds + cur + boff + nf * 1024);
#pragma unroll
        for (int mf = 0; mf < 4; ++mf)
            a[mf] = *(const bf16x8*)(lds + cur + aoff + mf * 1024);
        __builtin_amdgcn_s_barrier();
        asm volatile("s_waitcnt lgkmcnt(0)" ::: "memory");
        __builtin_amdgcn_sched_barrier(0);
        __builtin_amdgcn_s_setprio(1);
#pragma unroll
        for (int mf = 0; mf < 4; ++mf)
#pragma unroll
            for (int nf = 0; nf < 4; ++nf)
                acc[mf][nf] = __builtin_amdgcn_mfma_f32_16x16x32_bf16(
                    a[mf], b[nf], acc[mf][nf], 0, 0, 0);
        __builtin_amdgcn_s_setprio(0);
        __builtin_amdgcn_s_barrier();

        // ================= phase B: stage B-tile of S(t+3); MFMA mf 4..7 =====
        GLL(B0 + kk,                       db + ldsB_st);
        GLL(B0 + (size_t)128 * K_DIM + kk, db + ldsB_st + 8192);
#pragma unroll
        for (int mf = 0; mf < 4; ++mf)
            a[mf] = *(const bf16x8*)(lds + cur + aoff + 4096 + mf * 1024);
        __builtin_amdgcn_s_barrier();
        asm volatile("s_waitcnt lgkmcnt(0)" ::: "memory");
        __builtin_amdgcn_sched_barrier(0);
        __builtin_amdgcn_s_setprio(1);
#pragma unroll
        for (int mf = 0; mf < 4; ++mf)
#pragma unroll
            for (int nf = 0; nf < 4; ++nf)
                acc[4 + mf][nf] = __builtin_amdgcn_mfma_f32_16x16x32_bf16(
                    a[mf], b[nf], acc[4 + mf][nf], 0, 0, 0);
        __builtin_amdgcn_s_setprio(0);
        // keep S(t+2), S(t+3) (8 loads) in flight; guarantees S(t+1) landed
        asm volatile("s_waitcnt vmcnt(8)" ::: "memory");
        __builtin_amdgcn_s_barrier();
    }

    // ---- epilogue: bias + fast tanh, fp32 stores ----
    const int cn  = l & 15;
    const int cr4 = (l >> 4) * 4;
    float bv[4];
#pragma unroll
    for (int nf = 0; nf < 4; ++nf)
        bv[nf] = bias[bn * 256 + wc * 64 + nf * 16 + cn];

#pragma unroll
    for (int mf = 0; mf < 8; ++mf) {
        const size_t row0 = (size_t)bm * 256 + wr * 128 + mf * 16 + cr4;
#pragma unroll
        for (int nf = 0; nf < 4; ++nf) {
            const size_t col = (size_t)bn * 256 + wc * 64 + nf * 16 + cn;
#pragma unroll
            for (int r = 0; r < 4; ++r)
                C[(row0 + r) * N_DIM + col] = fast_tanh(acc[mf][nf][r] + bv[nf]);
        }
    }
#undef GLL
}

extern "C" void kernel_launch(void* const* d_in, const int* in_sizes, int n_in,
                              void* d_out, int out_size, void* d_ws, size_t ws_size,
                              hipStream_t stream) {
    const float* inputs = (const float*)d_in[0];   // [8192, 4096]
    const float* weight = (const float*)d_in[1];   // [4096, 4096]
    const float* bias   = (const float*)d_in[2];   // [4096]
    float* out = (float*)d_out;

    const size_t a_bytes = (size_t)B_DIM * K_DIM * sizeof(u16); // 67 MB
    const size_t b_bytes = (size_t)K_DIM * N_DIM * sizeof(u16); // 33.5 MB
    if (ws_size < a_bytes + b_bytes) return;

    u16* Abin = (u16*)d_ws;
    u16* Btb  = (u16*)((char*)d_ws + a_bytes);

    binarize_a_kernel<<<2048, 256, 0, stream>>>(inputs, Abin, (long)B_DIM * K_DIM / 8);

    dim3 tgrid(N_DIM / 32, K_DIM / 32);
    bintrans_kernel<<<tgrid, dim3(32, 8), 0, stream>>>(weight, Btb);

    bgemm_kernel<<<(B_DIM / 256) * (N_DIM / 256), 512, 0, stream>>>(Abin, Btb, bias, out);
}

// Round 3
// 394.043 us; speedup vs baseline: 1.6001x; 1.2403x over previous
//
#include <hip/hip_runtime.h>

// out = tanh(sign(X) @ sign(W) + bias)
//   X: [8192,4096] fp32, W: [4096,4096] fp32, bias: [4096] fp32, out fp32.
// Binarize to int8 +-1 (exact; i32 accumulation of +-1 over K=4096 is exact),
// then 256x256-tile i8 MFMA GEMM (mfma_i32_16x16x64_i8, ~2x bf16 rate) with the
// counted-vmcnt 4-buffer LDS ring pipeline and XOR-swizzled LDS (verified 0-conflict).
// Byte geometry identical to the round-2 bf16 kernel: BK=64 i8 = 64 B/row.

#define B_DIM 8192
#define K_DIM 4096
#define N_DIM 4096
#define BK 64             // i8 elements per K-tile = 64 bytes/row
#define NT (K_DIM / BK)   // 64 K-tiles

typedef int   i32x4 __attribute__((ext_vector_type(4)));
typedef unsigned char u8;

__device__ __forceinline__ unsigned char binq8(float v) {
    return (v < 0.0f) ? 0xFFu : 0x01u;   // -1 : +1 ; x==0 -> +1 (matches jnp.where)
}

__device__ __forceinline__ float fast_tanh(float x) {
    float ax = __builtin_fabsf(x);
    float t  = __expf(-2.0f * ax);
    float r  = (1.0f - t) * __builtin_amdgcn_rcpf(1.0f + t);
    return __builtin_copysignf(r, x);
}

// ---- Prepass 1: binarize X -> i8 [B_DIM][K_DIM]; 16 floats -> 16B store ----
__global__ __launch_bounds__(256) void binarize_a_kernel(
    const float* __restrict__ in, u8* __restrict__ out, long n16) {
    long i = (long)blockIdx.x * blockDim.x + threadIdx.x;
    const long stride = (long)gridDim.x * blockDim.x;
    for (; i < n16; i += stride) {
        const float4* p = (const float4*)in + 4 * i;
        float4 v0 = p[0], v1 = p[1], v2 = p[2], v3 = p[3];
        unsigned int w0 = (unsigned)binq8(v0.x) | ((unsigned)binq8(v0.y) << 8)
                        | ((unsigned)binq8(v0.z) << 16) | ((unsigned)binq8(v0.w) << 24);
        unsigned int w1 = (unsigned)binq8(v1.x) | ((unsigned)binq8(v1.y) << 8)
                        | ((unsigned)binq8(v1.z) << 16) | ((unsigned)binq8(v1.w) << 24);
        unsigned int w2 = (unsigned)binq8(v2.x) | ((unsigned)binq8(v2.y) << 8)
                        | ((unsigned)binq8(v2.z) << 16) | ((unsigned)binq8(v2.w) << 24);
        unsigned int w3 = (unsigned)binq8(v3.x) | ((unsigned)binq8(v3.y) << 8)
                        | ((unsigned)binq8(v3.z) << 16) | ((unsigned)binq8(v3.w) << 24);
        i32x4 o = {(int)w0, (int)w1, (int)w2, (int)w3};
        *(i32x4*)(out + i * 16) = o;
    }
}

// ---- Prepass 2: binarize + transpose W [K][N] -> Bt i8 [N][K] ----
// 64x64 tile, float4 loads, 16B transposed stores.
__global__ __launch_bounds__(256) void bintrans_kernel(
    const float* __restrict__ W, u8* __restrict__ Bt) {
    __shared__ u8 tile[64][64];
    const int n0  = blockIdx.x * 64;
    const int k0  = blockIdx.y * 64;
    const int tid = threadIdx.x;
    const int r   = tid >> 4;         // 0..15
    const int c4  = (tid & 15) * 4;   // 0..60
#pragma unroll
    for (int i = 0; i < 4; ++i) {
        const int k = i * 16 + r;
        float4 v = *(const float4*)(W + (size_t)(k0 + k) * N_DIM + n0 + c4);
        unsigned int p = (unsigned)binq8(v.x) | ((unsigned)binq8(v.y) << 8)
                       | ((unsigned)binq8(v.z) << 16) | ((unsigned)binq8(v.w) << 24);
        *(unsigned int*)&tile[k][c4] = p;
    }
    __syncthreads();
    const int n  = tid >> 2;          // 0..63
    const int ks = (tid & 3) * 16;    // 0,16,32,48
    unsigned int o[4];
#pragma unroll
    for (int q = 0; q < 4; ++q) {
        unsigned int p = 0;
#pragma unroll
        for (int j = 0; j < 4; ++j)
            p |= (unsigned)tile[ks + q * 4 + j][n] << (8 * j);
        o[q] = p;
    }
    i32x4 ov = {(int)o[0], (int)o[1], (int)o[2], (int)o[3]};
    *(i32x4*)(Bt + (size_t)(n0 + n) * K_DIM + k0 + ks) = ov;
}

// ---- Main GEMM: 256x256 tile, BK=64 i8, 8 waves (2Mx4N), wave tile 128x64 ----
// LDS: 4-buffer ring, each buffer = A[256][64B] + B[256][64B] = 32 KB -> 128 KB.
// XOR swizzle identical (byte-level) to the verified bf16 kernel: row r's 16B
// slot s holds logical slot s ^ ((r>>1)&3), applied to staging SOURCE and ds_read.
// Pipeline: prefetch distance 3 tiles; vmcnt(8) once per tile (never 0 in loop).
__global__ __launch_bounds__(512, 2) void bgemm_kernel(
    const u8* __restrict__ A,
    const u8* __restrict__ Bt,
    const float* __restrict__ bias,
    float* __restrict__ C) {

    __shared__ __align__(1024) char lds[131072];

    const int tid = threadIdx.x;
    const int l   = tid & 63;
    const int w   = tid >> 6;     // 0..7
    const int wr  = w >> 2;       // 0..1
    const int wc  = w & 3;        // 0..3

    // XCD-aware bijective swizzle (grid = 512, divisible by 8)
    const int wg  = blockIdx.x;
    const int per = gridDim.x >> 3;
    const int swz = (wg & 7) * per + (wg >> 3);
    const int NBN = N_DIM / 256;          // 16
    const int bm  = swz / NBN;
    const int bn  = swz % NBN;

    // staging: row = tid>>2 (0..127), slot = tid&3 (16B each);
    // source logical slot = (tid&3) ^ ((row>>1)&3) = (tid&3) ^ ((tid>>3)&3)
    const int sslot = (tid & 3) ^ ((tid >> 3) & 3);
    const u8* A0 = A  + (size_t)(bm * 256 + (tid >> 2)) * K_DIM + sslot * 16;
    const u8* B0 = Bt + (size_t)(bn * 256 + (tid >> 2)) * K_DIM + sslot * 16;
    const int ldsA_st = w * 1024;            // + i*8192 + bufbase
    const int ldsB_st = 16384 + w * 1024;

    // fragment reads: row = fragbase + (l&15), k-slot g = l>>4 (16 i8 = 16B);
    // swizzled slot = g ^ ((l>>1)&3)  (fragbase multiple of 16)
    const int colb = ((l >> 4) ^ ((l >> 1) & 3)) << 4;
    const int aoff = (wr * 128 + (l & 15)) * 64 + colb;            // A region
    const int boff = 16384 + (wc * 64 + (l & 15)) * 64 + colb;     // B region

#define GLL(srcp, ldsoff)                                                        \
    __builtin_amdgcn_global_load_lds(                                            \
        (const __attribute__((address_space(1))) void*)(srcp),                   \
        (__attribute__((address_space(3))) void*)(lds + (ldsoff)), 16, 0, 0)

    i32x4 acc[8][4];
#pragma unroll
    for (int mf = 0; mf < 8; ++mf)
#pragma unroll
        for (int nf = 0; nf < 4; ++nf) acc[mf][nf] = (i32x4){0, 0, 0, 0};

    // ---- prologue: stage tiles 0,1,2 into ring buffers 0,1,2 (12 loads) ----
#pragma unroll
    for (int tp = 0; tp < 3; ++tp) {
        const int db = tp << 15;
        const int kk = tp * BK;
        GLL(A0 + kk,                          db + ldsA_st);
        GLL(A0 + (size_t)128 * K_DIM + kk,    db + ldsA_st + 8192);
        GLL(B0 + kk,                          db + ldsB_st);
        GLL(B0 + (size_t)128 * K_DIM + kk,    db + ldsB_st + 8192);
    }
    asm volatile("s_waitcnt vmcnt(8)" ::: "memory");   // tile 0 landed
    __builtin_amdgcn_s_barrier();

    for (int t = 0; t < NT; ++t) {
        const int cur = (t & 3) << 15;
        const int db  = ((t + 3) & 3) << 15;
        const int tp  = (t + 3 < NT) ? (t + 3) : 0;    // dummy re-stage at tail
        const int kk  = tp * BK;

        i32x4 a[4], b[4];

        // ===== phase A: stage A-half of tile t+3; MFMA mf 0..3 =====
        GLL(A0 + kk,                       db + ldsA_st);
        GLL(A0 + (size_t)128 * K_DIM + kk, db + ldsA_st + 8192);
#pragma unroll
        for (int nf = 0; nf < 4; ++nf)
            b[nf] = *(const i32x4*)(lds + cur + boff + nf * 1024);
#pragma unroll
        for (int mf = 0; mf < 4; ++mf)
            a[mf] = *(const i32x4*)(lds + cur + aoff + mf * 1024);
        __builtin_amdgcn_s_barrier();
        asm volatile("s_waitcnt lgkmcnt(0)" ::: "memory");
        __builtin_amdgcn_sched_barrier(0);
        __builtin_amdgcn_s_setprio(1);
#pragma unroll
        for (int mf = 0; mf < 4; ++mf)
#pragma unroll
            for (int nf = 0; nf < 4; ++nf)
                acc[mf][nf] = __builtin_amdgcn_mfma_i32_16x16x64_i8(
                    a[mf], b[nf], acc[mf][nf], 0, 0, 0);
        __builtin_amdgcn_s_setprio(0);
        __builtin_amdgcn_s_barrier();

        // ===== phase B: stage B-half of tile t+3; MFMA mf 4..7 =====
        GLL(B0 + kk,                       db + ldsB_st);
        GLL(B0 + (size_t)128 * K_DIM + kk, db + ldsB_st + 8192);
#pragma unroll
        for (int mf = 0; mf < 4; ++mf)
            a[mf] = *(const i32x4*)(lds + cur + aoff + 4096 + mf * 1024);
        __builtin_amdgcn_s_barrier();
        asm volatile("s_waitcnt lgkmcnt(0)" ::: "memory");
        __builtin_amdgcn_sched_barrier(0);
        __builtin_amdgcn_s_setprio(1);
#pragma unroll
        for (int mf = 0; mf < 4; ++mf)
#pragma unroll
            for (int nf = 0; nf < 4; ++nf)
                acc[4 + mf][nf] = __builtin_amdgcn_mfma_i32_16x16x64_i8(
                    a[mf], b[nf], acc[4 + mf][nf], 0, 0, 0);
        __builtin_amdgcn_s_setprio(0);
        // keep the 8 most recent loads (tiles t+2, t+3) in flight; t+1 landed
        asm volatile("s_waitcnt vmcnt(8)" ::: "memory");
        __builtin_amdgcn_s_barrier();
    }

    // ---- epilogue: i32 -> f32, bias + fast tanh ----
    const int cn  = l & 15;
    const int cr4 = (l >> 4) * 4;
    float bv[4];
#pragma unroll
    for (int nf = 0; nf < 4; ++nf)
        bv[nf] = bias[bn * 256 + wc * 64 + nf * 16 + cn];

#pragma unroll
    for (int mf = 0; mf < 8; ++mf) {
        const size_t row0 = (size_t)bm * 256 + wr * 128 + mf * 16 + cr4;
#pragma unroll
        for (int nf = 0; nf < 4; ++nf) {
            const size_t col = (size_t)bn * 256 + wc * 64 + nf * 16 + cn;
#pragma unroll
            for (int r = 0; r < 4; ++r)
                C[(row0 + r) * N_DIM + col] =
                    fast_tanh((float)acc[mf][nf][r] + bv[nf]);
        }
    }
#undef GLL
}

extern "C" void kernel_launch(void* const* d_in, const int* in_sizes, int n_in,
                              void* d_out, int out_size, void* d_ws, size_t ws_size,
                              hipStream_t stream) {
    const float* inputs = (const float*)d_in[0];   // [8192, 4096]
    const float* weight = (const float*)d_in[1];   // [4096, 4096]
    const float* bias   = (const float*)d_in[2];   // [4096]
    float* out = (float*)d_out;

    const size_t a_bytes = (size_t)B_DIM * K_DIM;  // 33.5 MB (i8)
    const size_t b_bytes = (size_t)K_DIM * N_DIM;  // 16.8 MB (i8)
    if (ws_size < a_bytes + b_bytes) return;

    u8* Abin = (u8*)d_ws;
    u8* Btb  = (u8*)((char*)d_ws + a_bytes);

    binarize_a_kernel<<<2048, 256, 0, stream>>>(inputs, Abin, (long)B_DIM * K_DIM / 16);

    dim3 tgrid(N_DIM / 64, K_DIM / 64);
    bintrans_kernel<<<tgrid, 256, 0, stream>>>(weight, Btb);

    bgemm_kernel<<<(B_DIM / 256) * (N_DIM / 256), 512, 0, stream>>>(Abin, Btb, bias, out);
}

// Round 4
// 337.625 us; speedup vs baseline: 1.8675x; 1.1671x over previous
//
#include <hip/hip_runtime.h>

// out = tanh(sign(X) @ sign(W) + bias)
//   X: [8192,4096] fp32, W: [4096,4096] fp32, bias: [4096] fp32, out fp32.
// Binarize to MX-FP4 (E2M1 +-1 nibbles, scale E8M0=127 -> x1.0; exact),
// then 256x256-tile fp4 MFMA GEMM (mfma_scale_f32_16x16x128_f8f6f4, K=128/instr)
// with the counted-vmcnt 4-buffer LDS ring and the XOR swizzle verified 0-conflict
// in rounds 2-3. Byte geometry identical: BK=128 fp4 = 64 B/row = BK=64 i8.

#define B_DIM 8192
#define K_DIM 4096
#define N_DIM 4096
#define KB    (K_DIM / 2)     // 2048 bytes per fp4 row
#define BKB   64              // bytes per row per K-tile (= 128 fp4 elements)
#define NT    (K_DIM / 128)   // 32 K-tiles

typedef float f32x4 __attribute__((ext_vector_type(4)));
typedef int   i32x4 __attribute__((ext_vector_type(4)));
typedef int   i32x8 __attribute__((ext_vector_type(8)));
typedef unsigned char u8;

// E2M1: +1.0 = 0x2, -1.0 = 0xA ; x==0 -> +1 (matches jnp.where(x<0,-1,1))
__device__ __forceinline__ unsigned int nib4(float v) {
    return (v < 0.0f) ? 0xAu : 0x2u;
}

__device__ __forceinline__ float fast_tanh(float x) {
    float ax = __builtin_fabsf(x);
    float t  = __expf(-2.0f * ax);
    float r  = (1.0f - t) * __builtin_amdgcn_rcpf(1.0f + t);
    return __builtin_copysignf(r, x);
}

// ---- Prepass 1: binarize X -> fp4 [B_DIM][KB]; 32 floats -> 16B store ----
__global__ __launch_bounds__(256) void binarize_a_kernel(
    const float* __restrict__ in, u8* __restrict__ out, long n32) {
    long i = (long)blockIdx.x * blockDim.x + threadIdx.x;
    const long stride = (long)gridDim.x * blockDim.x;
    for (; i < n32; i += stride) {
        const float4* p = (const float4*)in + 8 * i;
        unsigned int w[4];
#pragma unroll
        for (int q = 0; q < 4; ++q) {
            float4 a = p[2 * q], b = p[2 * q + 1];
            w[q] = nib4(a.x)        | (nib4(a.y) << 4)  | (nib4(a.z) << 8)
                 | (nib4(a.w) << 12)| (nib4(b.x) << 16) | (nib4(b.y) << 20)
                 | (nib4(b.z) << 24)| (nib4(b.w) << 28);
        }
        i32x4 o = {(int)w[0], (int)w[1], (int)w[2], (int)w[3]};
        *(i32x4*)(out + i * 16) = o;
    }
}

// ---- Prepass 2: binarize + transpose W [K][N] -> Bt fp4 [N][KB] ----
__global__ __launch_bounds__(256) void bintrans_kernel(
    const float* __restrict__ W, u8* __restrict__ Bt) {
    __shared__ u8 tile[64][64];     // nibble values stored as bytes
    const int n0  = blockIdx.x * 64;
    const int k0  = blockIdx.y * 64;
    const int tid = threadIdx.x;
    const int r   = tid >> 4;         // 0..15
    const int c4  = (tid & 15) * 4;   // 0..60
#pragma unroll
    for (int i = 0; i < 4; ++i) {
        const int k = i * 16 + r;
        float4 v = *(const float4*)(W + (size_t)(k0 + k) * N_DIM + n0 + c4);
        unsigned int p = nib4(v.x) | (nib4(v.y) << 8) | (nib4(v.z) << 16)
                       | (nib4(v.w) << 24);
        *(unsigned int*)&tile[k][c4] = p;
    }
    __syncthreads();
    const int n  = tid >> 2;          // 0..63
    const int ks = (tid & 3) * 16;    // k start: 0,16,32,48
    unsigned int lo = 0, hi = 0;
#pragma unroll
    for (int j = 0; j < 8; ++j) lo |= (unsigned)tile[ks + j][n]     << (4 * j);
#pragma unroll
    for (int j = 0; j < 8; ++j) hi |= (unsigned)tile[ks + 8 + j][n] << (4 * j);
    uint2 o; o.x = lo; o.y = hi;
    *(uint2*)(Bt + (size_t)(n0 + n) * KB + ((k0 + ks) >> 1)) = o;
}

// ---- Main GEMM: 256x256 tile, BK=128 fp4 (64 B/row), 8 waves (2Mx4N) ----
// LDS: 4-buffer ring, buffer = A[256][64B] + B[256][64B] = 32 KB -> 128 KB.
// XOR swizzle (byte-identical to verified r2/r3): row r's 16B slot s holds
// logical slot s ^ ((r>>1)&3); applied to staging SOURCE and ds_read address.
// Pipeline: prefetch depth 3; vmcnt(8) once per tile (never 0 in loop).
__global__ __launch_bounds__(512, 2) void bgemm_kernel(
    const u8* __restrict__ A,
    const u8* __restrict__ Bt,
    const float* __restrict__ bias,
    float* __restrict__ C) {

    __shared__ __align__(1024) char lds[131072];

    const int tid = threadIdx.x;
    const int l   = tid & 63;
    const int w   = tid >> 6;     // 0..7
    const int wr  = w >> 2;       // 0..1
    const int wc  = w & 3;        // 0..3

    // XCD-aware bijective swizzle (grid = 512, divisible by 8)
    const int wg  = blockIdx.x;
    const int per = gridDim.x >> 3;
    const int swz = (wg & 7) * per + (wg >> 3);
    const int NBN = N_DIM / 256;          // 16
    const int bm  = swz / NBN;
    const int bn  = swz % NBN;

    // staging: row = tid>>2 (0..127), phys slot = tid&3 (16B);
    // source logical slot = (tid&3) ^ ((row>>1)&3) = (tid&3) ^ ((tid>>3)&3)
    const int sslot = (tid & 3) ^ ((tid >> 3) & 3);
    const u8* A0 = A  + (size_t)(bm * 256 + (tid >> 2)) * KB + sslot * 16;
    const u8* B0 = Bt + (size_t)(bn * 256 + (tid >> 2)) * KB + sslot * 16;
    const int ldsA_st = w * 1024;            // + i*8192 + bufbase
    const int ldsB_st = 16384 + w * 1024;

    // fragment reads: row = fragbase + (l&15), k-slot g = l>>4 (32 fp4 = 16B);
    // swizzled slot = g ^ ((l>>1)&3)  (fragbase multiple of 16)
    const int colb = ((l >> 4) ^ ((l >> 1) & 3)) << 4;
    const int aoff = (wr * 128 + (l & 15)) * 64 + colb;            // A region
    const int boff = 16384 + (wc * 64 + (l & 15)) * 64 + colb;     // B region

#define GLL(srcp, ldsoff)                                                        \
    __builtin_amdgcn_global_load_lds(                                            \
        (const __attribute__((address_space(1))) void*)(srcp),                   \
        (__attribute__((address_space(3))) void*)(lds + (ldsoff)), 16, 0, 0)

    f32x4 acc[8][4];
#pragma unroll
    for (int mf = 0; mf < 8; ++mf)
#pragma unroll
        for (int nf = 0; nf < 4; ++nf) acc[mf][nf] = (f32x4){0.f, 0.f, 0.f, 0.f};

    const i32x4 z4 = {0, 0, 0, 0};

    // ---- prologue: stage tiles 0,1,2 into ring buffers 0,1,2 (12 loads) ----
#pragma unroll
    for (int tp = 0; tp < 3; ++tp) {
        const int db = tp << 15;
        const int kk = tp * BKB;
        GLL(A0 + kk,                       db + ldsA_st);
        GLL(A0 + (size_t)128 * KB + kk,    db + ldsA_st + 8192);
        GLL(B0 + kk,                       db + ldsB_st);
        GLL(B0 + (size_t)128 * KB + kk,    db + ldsB_st + 8192);
    }
    asm volatile("s_waitcnt vmcnt(8)" ::: "memory");   // tile 0 landed
    __builtin_amdgcn_s_barrier();

    for (int t = 0; t < NT; ++t) {
        const int cur = (t & 3) << 15;
        const int db  = ((t + 3) & 3) << 15;
        const int tp  = (t + 3 < NT) ? (t + 3) : 0;    // dummy re-stage at tail
        const int kk  = tp * BKB;

        i32x4 at[4], bt[4];
        i32x8 a8[4], b8[4];

        // ===== phase A: stage A-half of tile t+3; MFMA mf 0..3 =====
        GLL(A0 + kk,                    db + ldsA_st);
        GLL(A0 + (size_t)128 * KB + kk, db + ldsA_st + 8192);
#pragma unroll
        for (int nf = 0; nf < 4; ++nf)
            bt[nf] = *(const i32x4*)(lds + cur + boff + nf * 1024);
#pragma unroll
        for (int mf = 0; mf < 4; ++mf)
            at[mf] = *(const i32x4*)(lds + cur + aoff + mf * 1024);
        __builtin_amdgcn_s_barrier();
        asm volatile("s_waitcnt lgkmcnt(0)" ::: "memory");
        __builtin_amdgcn_sched_barrier(0);
#pragma unroll
        for (int nf = 0; nf < 4; ++nf)
            b8[nf] = __builtin_shufflevector(bt[nf], z4, 0, 1, 2, 3, 4, 5, 6, 7);
#pragma unroll
        for (int mf = 0; mf < 4; ++mf)
            a8[mf] = __builtin_shufflevector(at[mf], z4, 0, 1, 2, 3, 4, 5, 6, 7);
        __builtin_amdgcn_s_setprio(1);
#pragma unroll
        for (int mf = 0; mf < 4; ++mf)
#pragma unroll
            for (int nf = 0; nf < 4; ++nf)
                acc[mf][nf] = __builtin_amdgcn_mfma_scale_f32_16x16x128_f8f6f4(
                    a8[mf], b8[nf], acc[mf][nf],
                    4, 4,                       // cbsz=FP4(A), blgp=FP4(B)
                    0, 0x7F7F7F7F,              // opselA, scaleA (E8M0 127 = 1.0)
                    0, 0x7F7F7F7F);             // opselB, scaleB
        __builtin_amdgcn_s_setprio(0);
        __builtin_amdgcn_s_barrier();

        // ===== phase B: stage B-half of tile t+3; MFMA mf 4..7 =====
        GLL(B0 + kk,                    db + ldsB_st);
        GLL(B0 + (size_t)128 * KB + kk, db + ldsB_st + 8192);
#pragma unroll
        for (int mf = 0; mf < 4; ++mf)
            at[mf] = *(const i32x4*)(lds + cur + aoff + 4096 + mf * 1024);
        __builtin_amdgcn_s_barrier();
        asm volatile("s_waitcnt lgkmcnt(0)" ::: "memory");
        __builtin_amdgcn_sched_barrier(0);
#pragma unroll
        for (int mf = 0; mf < 4; ++mf)
            a8[mf] = __builtin_shufflevector(at[mf], z4, 0, 1, 2, 3, 4, 5, 6, 7);
        __builtin_amdgcn_s_setprio(1);
#pragma unroll
        for (int mf = 0; mf < 4; ++mf)
#pragma unroll
            for (int nf = 0; nf < 4; ++nf)
                acc[4 + mf][nf] = __builtin_amdgcn_mfma_scale_f32_16x16x128_f8f6f4(
                    a8[mf], b8[nf], acc[4 + mf][nf],
                    4, 4, 0, 0x7F7F7F7F, 0, 0x7F7F7F7F);
        __builtin_amdgcn_s_setprio(0);
        // keep the 8 most recent loads (tiles t+2, t+3) in flight; t+1 landed
        asm volatile("s_waitcnt vmcnt(8)" ::: "memory");
        __builtin_amdgcn_s_barrier();
    }

    // ---- epilogue: bias + fast tanh, fp32 stores ----
    const int cn  = l & 15;
    const int cr4 = (l >> 4) * 4;
    float bv[4];
#pragma unroll
    for (int nf = 0; nf < 4; ++nf)
        bv[nf] = bias[bn * 256 + wc * 64 + nf * 16 + cn];

#pragma unroll
    for (int mf = 0; mf < 8; ++mf) {
        const size_t row0 = (size_t)bm * 256 + wr * 128 + mf * 16 + cr4;
#pragma unroll
        for (int nf = 0; nf < 4; ++nf) {
            const size_t col = (size_t)bn * 256 + wc * 64 + nf * 16 + cn;
#pragma unroll
            for (int r = 0; r < 4; ++r)
                C[(row0 + r) * N_DIM + col] = fast_tanh(acc[mf][nf][r] + bv[nf]);
        }
    }
#undef GLL
}

extern "C" void kernel_launch(void* const* d_in, const int* in_sizes, int n_in,
                              void* d_out, int out_size, void* d_ws, size_t ws_size,
                              hipStream_t stream) {
    const float* inputs = (const float*)d_in[0];   // [8192, 4096]
    const float* weight = (const float*)d_in[1];   // [4096, 4096]
    const float* bias   = (const float*)d_in[2];   // [4096]
    float* out = (float*)d_out;

    const size_t a_bytes = (size_t)B_DIM * KB;  // 16.8 MB (fp4)
    const size_t b_bytes = (size_t)N_DIM * KB;  // 8.4 MB (fp4)
    if (ws_size < a_bytes + b_bytes) return;

    u8* Abin = (u8*)d_ws;
    u8* Btb  = (u8*)((char*)d_ws + a_bytes);

    binarize_a_kernel<<<2048, 256, 0, stream>>>(inputs, Abin, (long)B_DIM * K_DIM / 32);

    dim3 tgrid(N_DIM / 64, K_DIM / 64);
    bintrans_kernel<<<tgrid, 256, 0, stream>>>(weight, Btb);

    bgemm_kernel<<<(B_DIM / 256) * (N_DIM / 256), 512, 0, stream>>>(Abin, Btb, bias, out);
}